// Round 1
// baseline (11134.264 us; speedup 1.0000x reference)
//
#include <hip/hip_runtime.h>

typedef unsigned short u16;
typedef unsigned int u32;
typedef __bf16 bf16x8 __attribute__((ext_vector_type(8)));
typedef float f32x4 __attribute__((ext_vector_type(4)));

#define YD 32
#define ZD 64
#define HD 256
#define RD 256
#define TSTEPS 199   // T-1 scan steps
#define BB 2048
#define MROWS 32     // batch rows per block
#define NBLK 64      // 2048/32
#define NTHR 512     // 8 waves
#define CATS 392     // [x(32)|y(32)|z(64)|h(256)] = 384 + 8 pad (2-way LDS bank aliasing = free)
#define HBS  264     // 256 + 8 pad

// bf16 weight layout offsets inside d_ws (element units, (N,K) row-major, K contiguous)
enum : int {
  OFF_ENC_W1 = 0,        // 256x320
  OFF_ENC_W2 = 81920,    // 256x256
  OFF_ENC_H  = 147456,   // [enc_mw;enc_sw] 128x256
  OFF_PRI_W1 = 180224,   // 256x288
  OFF_PRI_W2 = 253952,   // 256x256
  OFF_PRI_H  = 319488,   // [pri_mw;pri_sw] 128x256
  OFF_DEC_W1 = 352256,   // 256x352
  OFF_DEC_W2 = 442368,   // 256x256
  OFF_DEC_H  = 507904,   // [dec_mw;dec_sw] 64x256
  OFF_GWIH   = 524288,   // 768x96
  OFF_GWHH   = 598016,   // 768x256
};

__device__ __forceinline__ u16 f2bf(float f) {
  u32 u = __float_as_uint(f);
  u += 0x7fffu + ((u >> 16) & 1u);   // RTNE
  return (u16)(u >> 16);
}
__device__ __forceinline__ float softplus_f(float x) {
  float l = __logf(1.f + __expf(-fabsf(x)));
  return x > 0.f ? x + l : l;
}
__device__ __forceinline__ float sigmoid_f(float x) {
  return __builtin_amdgcn_rcpf(1.f + __expf(-x));
}
__device__ __forceinline__ float tanh_f(float x) {
  float e = __expf(-2.f * fabsf(x));
  float t = (1.f - e) * __builtin_amdgcn_rcpf(1.f + e);
  return x >= 0.f ? t : -t;
}

// Wave-level GEMM over one contiguous K-segment.
// A (LDS, row-major, stride AS elems): rows (rt0+rt)*16 + (lane&15), cols acol0 + ks*32 + quad*8
// W (global bf16, (N,Kw) row-major):   rows wrow0 + nt*16 + (lane&15), cols wk0 + ks*32 + quad*8
// D[m][n] += sum_k A[m][k]*W[n][k]  (i.e. act @ W.T, matching the reference)
template<int NT, int RT, int KS, int AS>
__device__ __forceinline__ void gemm_seg(f32x4 (&acc)[NT][RT],
    const u16* __restrict__ W, const int Kw, const int wrow0, const int wk0,
    const u16* A, const int acol0, const int rt0, const int lane)
{
  const int n = lane & 15, quad = lane >> 4;
  #pragma unroll
  for (int ks = 0; ks < KS; ++ks) {
    bf16x8 a[RT];
    #pragma unroll
    for (int rt = 0; rt < RT; ++rt)
      a[rt] = *reinterpret_cast<const bf16x8*>(A + ((rt0 + rt) * 16 + n) * AS + acol0 + ks * 32 + quad * 8);
    #pragma unroll
    for (int nt = 0; nt < NT; ++nt) {
      bf16x8 b = *reinterpret_cast<const bf16x8*>(W + (size_t)(wrow0 + nt * 16 + n) * Kw + wk0 + ks * 32 + quad * 8);
      #pragma unroll
      for (int rt = 0; rt < RT; ++rt)
        acc[nt][rt] = __builtin_amdgcn_mfma_f32_16x16x32_bf16(a[rt], b, acc[nt][rt], 0, 0, 0);
    }
  }
}

// bias + ReLU + bf16 store of D tiles to LDS (C-layout: row = rt*16+quad*4+i, col = col0+nt*16+n)
template<int NT, int RT, int DS>
__device__ __forceinline__ void store_relu(const f32x4 (&acc)[NT][RT], u16* dst,
    const int col0, const int rt0, const float* __restrict__ bias, const int lane)
{
  const int n = lane & 15, quad = lane >> 4;
  #pragma unroll
  for (int nt = 0; nt < NT; ++nt) {
    const float b = bias[col0 + nt * 16 + n];
    #pragma unroll
    for (int rt = 0; rt < RT; ++rt)
      #pragma unroll
      for (int i = 0; i < 4; ++i) {
        float v = fmaxf(acc[nt][rt][i] + b, 0.f);
        dst[((rt0 + rt) * 16 + quad * 4 + i) * DS + col0 + nt * 16 + n] = f2bf(v);
      }
  }
}

struct PrepArgs { const float* src[14]; int off[14]; int cnt[14]; };

__global__ void prep_weights(PrepArgs a, u16* __restrict__ dst) {
  const int j = blockIdx.y;
  const float* __restrict__ s = a.src[j];
  u16* d = dst + a.off[j];
  const int nel = a.cnt[j];
  for (int i = blockIdx.x * blockDim.x + threadIdx.x; i < nel; i += gridDim.x * blockDim.x)
    d[i] = f2bf(s[i]);
}

__global__ void zero_out_k(float* out) { if (threadIdx.x < 2) out[threadIdx.x] = 0.f; }

__global__ __launch_bounds__(NTHR, 1)
void vrnn_kernel(const float* __restrict__ states, const float* __restrict__ eps,
                 const float* __restrict__ enc_b1, const float* __restrict__ enc_b2,
                 const float* __restrict__ enc_mb, const float* __restrict__ enc_sb,
                 const float* __restrict__ pri_b1, const float* __restrict__ pri_b2,
                 const float* __restrict__ pri_mb, const float* __restrict__ pri_sb,
                 const float* __restrict__ dec_b1, const float* __restrict__ dec_b2,
                 const float* __restrict__ dec_mb, const float* __restrict__ dec_sb,
                 const float* __restrict__ gbih, const float* __restrict__ gbhh,
                 const u16* __restrict__ ws, float* __restrict__ out)
{
  __shared__ u16 cat[MROWS * CATS];   // [x|y|z|h] staging, bf16
  __shared__ u16 hb1[MROWS * HBS];    // layer-1 outputs
  __shared__ u16 hb2[MROWS * HBS];    // layer-2 outputs

  const int tid = threadIdx.x;
  const int w = tid >> 6, lane = tid & 63;
  const int n = lane & 15, quad = lane >> 4;
  const int r0 = blockIdx.x * MROWS;
  const int n0 = w * 32;            // this wave's 32-col strip for N=256-wide layers
  const int ctH = w & 3, rtH = w >> 2; // head (col-group, row-tile) assignment

  // zero the h region of cat (h0 = 0)
  for (int i = tid; i < MROWS * (HD / 2); i += NTHR) {
    int row = i >> 7, c = (i & 127) * 2;
    *reinterpret_cast<u32*>(&cat[row * CATS + 128 + c]) = 0u;
  }

  float hreg[2][2][4];  // fp32 master h, C-layout: [nt][rt][i] -> row rt*16+quad*4+i, col n0+nt*16+n
  #pragma unroll
  for (int a = 0; a < 2; ++a)
    #pragma unroll
    for (int b = 0; b < 2; ++b)
      #pragma unroll
      for (int c = 0; c < 4; ++c) hreg[a][b][c] = 0.f;

  float kl_acc = 0.f, nll_acc = 0.f;
  float emv[4], esv[4];

  for (int t = 0; t < TSTEPS; ++t) {
    // ---- stage x=states[t+1] (waves 0-3) and y=states[t] (waves 4-7) into cat ----
    {
      const int tt = tid & 255, row = tt >> 3, c4 = (tt & 7) * 4;
      const size_t tsel = (tid < 256) ? (size_t)(t + 1) : (size_t)t;
      const float4 v = *reinterpret_cast<const float4*>(states + (tsel * BB + r0 + row) * YD + c4);
      u16* d = cat + row * CATS + ((tid < 256) ? 0 : 32) + c4;
      d[0] = f2bf(v.x); d[1] = f2bf(v.y); d[2] = f2bf(v.z); d[3] = f2bf(v.w);
    }
    __syncthreads();

    // ---- enc layer 1: [x,y,h] (K=320) -> hb1 ----
    {
      f32x4 acc[2][2] = {};
      gemm_seg<2, 2, 2, CATS>(acc, ws + OFF_ENC_W1, 320, n0, 0, cat, 0, 0, lane);    // x,y
      gemm_seg<2, 2, 8, CATS>(acc, ws + OFF_ENC_W1, 320, n0, 64, cat, 128, 0, lane); // h
      store_relu<2, 2, HBS>(acc, hb1, n0, 0, enc_b1, lane);
    }
    __syncthreads();

    // ---- enc layer 2 -> hb2 ----
    {
      f32x4 acc[2][2] = {};
      gemm_seg<2, 2, 8, HBS>(acc, ws + OFF_ENC_W2, 256, n0, 0, hb1, 0, 0, lane);
      store_relu<2, 2, HBS>(acc, hb2, n0, 0, enc_b2, lane);
    }
    __syncthreads();

    // ---- enc heads (em, es) + z sample -> cat[z]; then pri layer 1 -> hb1 ----
    {
      f32x4 am[1][1] = {}, as[1][1] = {};
      gemm_seg<1, 1, 8, HBS>(am, ws + OFF_ENC_H, 256, ctH * 16, 0, hb2, 0, rtH, lane);
      gemm_seg<1, 1, 8, HBS>(as, ws + OFF_ENC_H, 256, 64 + ctH * 16, 0, hb2, 0, rtH, lane);
      const int j = ctH * 16 + n;
      #pragma unroll
      for (int i = 0; i < 4; ++i) {
        const int m = rtH * 16 + quad * 4 + i;
        float em = am[0][0][i] + enc_mb[j];
        float es = softplus_f(as[0][0][i] + enc_sb[j]);
        emv[i] = em; esv[i] = es;
        float e = eps[((size_t)t * BB + r0 + m) * ZD + j];
        cat[m * CATS + 64 + j] = f2bf(em + es * e);
      }
      f32x4 acc[2][2] = {};
      gemm_seg<2, 2, 1, CATS>(acc, ws + OFF_PRI_W1, 288, n0, 0, cat, 32, 0, lane);   // y
      gemm_seg<2, 2, 8, CATS>(acc, ws + OFF_PRI_W1, 288, n0, 32, cat, 128, 0, lane); // h
      store_relu<2, 2, HBS>(acc, hb1, n0, 0, pri_b1, lane);
    }
    __syncthreads();

    // ---- pri layer 2 -> hb2 ----
    {
      f32x4 acc[2][2] = {};
      gemm_seg<2, 2, 8, HBS>(acc, ws + OFF_PRI_W2, 256, n0, 0, hb1, 0, 0, lane);
      store_relu<2, 2, HBS>(acc, hb2, n0, 0, pri_b2, lane);
    }
    __syncthreads();

    // ---- pri heads (pm, ps) + KL; then dec layer 1 ([y,z,h], K=352) -> hb1 ----
    {
      f32x4 am[1][1] = {}, as[1][1] = {};
      gemm_seg<1, 1, 8, HBS>(am, ws + OFF_PRI_H, 256, ctH * 16, 0, hb2, 0, rtH, lane);
      gemm_seg<1, 1, 8, HBS>(as, ws + OFF_PRI_H, 256, 64 + ctH * 16, 0, hb2, 0, rtH, lane);
      const int j = ctH * 16 + n;
      #pragma unroll
      for (int i = 0; i < 4; ++i) {
        float pm = am[0][0][i] + pri_mb[j];
        float ps = softplus_f(as[0][0][i] + pri_sb[j]);
        float es = esv[i], em = emv[i];
        float d = em - pm;
        kl_acc += 0.5f * (2.f * __logf(ps * __builtin_amdgcn_rcpf(es))
                          + (es * es + d * d) / (ps * ps) - 1.f);
      }
      f32x4 acc[2][2] = {};
      gemm_seg<2, 2, 3, CATS>(acc, ws + OFF_DEC_W1, 352, n0, 0, cat, 32, 0, lane);   // y,z
      gemm_seg<2, 2, 8, CATS>(acc, ws + OFF_DEC_W1, 352, n0, 96, cat, 128, 0, lane); // h
      store_relu<2, 2, HBS>(acc, hb1, n0, 0, dec_b1, lane);
    }
    __syncthreads();

    // ---- dec layer 2 -> hb2 ----
    {
      f32x4 acc[2][2] = {};
      gemm_seg<2, 2, 8, HBS>(acc, ws + OFF_DEC_W2, 256, n0, 0, hb1, 0, 0, lane);
      store_relu<2, 2, HBS>(acc, hb2, n0, 0, dec_b2, lane);
    }
    __syncthreads();

    // ---- dec heads (dm, ds) + NLL (waves 0-3); GRU GEMMs + gates (all waves) ----
    {
      if (w < 4) {
        const int p = w & 1, rtb = w >> 1;
        f32x4 am[1][1] = {}, as[1][1] = {};
        gemm_seg<1, 1, 8, HBS>(am, ws + OFF_DEC_H, 256, p * 16, 0, hb2, 0, rtb, lane);
        gemm_seg<1, 1, 8, HBS>(as, ws + OFF_DEC_H, 256, 32 + p * 16, 0, hb2, 0, rtb, lane);
        const int j = p * 16 + n;
        #pragma unroll
        for (int i = 0; i < 4; ++i) {
          const int m = rtb * 16 + quad * 4 + i;
          float dm = am[0][0][i] + dec_mb[j];
          float ds = softplus_f(as[0][0][i] + dec_sb[j]);
          float xv = states[((size_t)(t + 1) * BB + r0 + m) * YD + j];
          float dd = xv - dm;
          nll_acc += __logf(ds) + dd * dd / (2.f * ds * ds) + 0.91893853320467274178f;
        }
      }
      // GRU: torch gate order [r,z,n]; gi = [x,z] @ Wih.T, gh = h @ Whh.T
      f32x4 aR[2][2] = {}, aU[2][2] = {}, aN[2][2] = {}, aH[2][2] = {};
      gemm_seg<2, 2, 1, CATS>(aR, ws + OFF_GWIH, 96, n0, 0, cat, 0, 0, lane);           // x
      gemm_seg<2, 2, 2, CATS>(aR, ws + OFF_GWIH, 96, n0, 32, cat, 64, 0, lane);          // z
      gemm_seg<2, 2, 8, CATS>(aR, ws + OFF_GWHH, 256, n0, 0, cat, 128, 0, lane);         // h
      gemm_seg<2, 2, 1, CATS>(aU, ws + OFF_GWIH, 96, RD + n0, 0, cat, 0, 0, lane);
      gemm_seg<2, 2, 2, CATS>(aU, ws + OFF_GWIH, 96, RD + n0, 32, cat, 64, 0, lane);
      gemm_seg<2, 2, 8, CATS>(aU, ws + OFF_GWHH, 256, RD + n0, 0, cat, 128, 0, lane);
      gemm_seg<2, 2, 1, CATS>(aN, ws + OFF_GWIH, 96, 2 * RD + n0, 0, cat, 0, 0, lane);
      gemm_seg<2, 2, 2, CATS>(aN, ws + OFF_GWIH, 96, 2 * RD + n0, 32, cat, 64, 0, lane);
      gemm_seg<2, 2, 8, CATS>(aH, ws + OFF_GWHH, 256, 2 * RD + n0, 0, cat, 128, 0, lane);
      #pragma unroll
      for (int nt = 0; nt < 2; ++nt) {
        const int j = n0 + nt * 16 + n;
        const float br = gbih[j] + gbhh[j];
        const float bu = gbih[RD + j] + gbhh[RD + j];
        const float bin = gbih[2 * RD + j];
        const float bhn = gbhh[2 * RD + j];
        #pragma unroll
        for (int rt = 0; rt < 2; ++rt)
          #pragma unroll
          for (int i = 0; i < 4; ++i) {
            float r = sigmoid_f(aR[nt][rt][i] + br);
            float u = sigmoid_f(aU[nt][rt][i] + bu);
            float nn = tanh_f(aN[nt][rt][i] + bin + r * (aH[nt][rt][i] + bhn));
            hreg[nt][rt][i] = (1.f - u) * nn + u * hreg[nt][rt][i];
          }
      }
    }
    __syncthreads();  // all reads of old cat-h/x/z complete before overwrite

    // ---- write h_new (bf16) back into cat[h]; next stage writes disjoint cols ----
    #pragma unroll
    for (int nt = 0; nt < 2; ++nt)
      #pragma unroll
      for (int rt = 0; rt < 2; ++rt)
        #pragma unroll
        for (int i = 0; i < 4; ++i)
          cat[(rt * 16 + quad * 4 + i) * CATS + 128 + n0 + nt * 16 + n] = f2bf(hreg[nt][rt][i]);
  }

  // ---- final reduction: wave shuffle + one atomic per wave ----
  float kv = kl_acc, nv = nll_acc;
  #pragma unroll
  for (int off = 32; off > 0; off >>= 1) {
    kv += __shfl_down(kv, off, 64);
    nv += __shfl_down(nv, off, 64);
  }
  if (lane == 0) {
    atomicAdd(out + 0, kv);
    atomicAdd(out + 1, nv);
  }
}

extern "C" void kernel_launch(void* const* d_in, const int* in_sizes, int n_in,
                              void* d_out, int out_size, void* d_ws, size_t ws_size,
                              hipStream_t stream) {
  const float* states = (const float*)d_in[0];
  const float* eps    = (const float*)d_in[1];
  u16* ws   = (u16*)d_ws;
  float* out = (float*)d_out;

  PrepArgs pa;
  const int jsrc[14] = {2, 4, 6, 8, 10, 12, 14, 16, 18, 20, 22, 24, 26, 27};
  const int joff[14] = {OFF_ENC_W1, OFF_ENC_W2, OFF_ENC_H, OFF_ENC_H + 16384,
                        OFF_PRI_W1, OFF_PRI_W2, OFF_PRI_H, OFF_PRI_H + 16384,
                        OFF_DEC_W1, OFF_DEC_W2, OFF_DEC_H, OFF_DEC_H + 8192,
                        OFF_GWIH, OFF_GWHH};
  const int jcnt[14] = {81920, 65536, 16384, 16384,
                        73728, 65536, 16384, 16384,
                        90112, 65536, 8192, 8192,
                        73728, 196608};
  for (int j = 0; j < 14; ++j) {
    pa.src[j] = (const float*)d_in[jsrc[j]];
    pa.off[j] = joff[j];
    pa.cnt[j] = jcnt[j];
  }

  zero_out_k<<<dim3(1), dim3(64), 0, stream>>>(out);
  prep_weights<<<dim3(64, 14), dim3(256), 0, stream>>>(pa, ws);
  vrnn_kernel<<<dim3(NBLK), dim3(NTHR), 0, stream>>>(
      states, eps,
      (const float*)d_in[3],  (const float*)d_in[5],
      (const float*)d_in[7],  (const float*)d_in[9],
      (const float*)d_in[11], (const float*)d_in[13],
      (const float*)d_in[15], (const float*)d_in[17],
      (const float*)d_in[19], (const float*)d_in[21],
      (const float*)d_in[23], (const float*)d_in[25],
      (const float*)d_in[28], (const float*)d_in[29],
      ws, out);
}